// Round 8
// baseline (393.360 us; speedup 1.0000x reference)
//
#include <hip/hip_runtime.h>
#include <hip/hip_bf16.h>

// ---- problem constants ----
#define HD 128          // head dim == hidden dim
#define NH 8            // heads
#define SQ 2048         // seq len
#define NROWS 4096      // B*S
#define RSQRT_D 0.08838834764831845f

typedef __bf16 bf16;
typedef bf16 bf16x8 __attribute__((ext_vector_type(8)));
typedef float f32x4 __attribute__((ext_vector_type(4)));

__device__ __forceinline__ f32x4 mfma16(bf16x8 a, bf16x8 b, f32x4 c) {
  return __builtin_amdgcn_mfma_f32_16x16x32_bf16(a, b, c, 0, 0, 0);
}
__device__ __forceinline__ bf16x8 ld8(const bf16* p) { return *(const bf16x8*)p; }
__device__ __forceinline__ unsigned short bfu(float v) {
  return __builtin_bit_cast(unsigned short, (bf16)v);
}
__device__ __forceinline__ unsigned packbf2(float a, float b) {
  return (unsigned)bfu(a) | ((unsigned)bfu(b) << 16);
}
__device__ __forceinline__ float bflo(unsigned u) {
  return __builtin_bit_cast(float, u << 16);
}
__device__ __forceinline__ float bfhi(unsigned u) {
  return __builtin_bit_cast(float, u & 0xffff0000u);
}

// ---------------- prep: x->bf16, adj->u8 ----------------
__global__ void k_prep_a(const float* __restrict__ x, const int* __restrict__ adj,
                         bf16* __restrict__ xb, unsigned char* __restrict__ mask8) {
  int idx = blockIdx.x * 256 + threadIdx.x;
  if (idx < NROWS * HD) { xb[idx] = (bf16)x[idx]; return; }
  int j = idx - NROWS * HD;
  if (j < (SQ * SQ / 4)) {
    int4 a = ((const int4*)adj)[j];
    uchar4 m;
    m.x = (unsigned char)a.x; m.y = (unsigned char)a.y;
    m.z = (unsigned char)a.z; m.w = (unsigned char)a.w;
    ((uchar4*)mask8)[j] = m;
  }
}

// ---------------- prep: weights -> bf16, [n][k] layout ----------------
__global__ void k_prep_w(const float* __restrict__ Wq, const float* __restrict__ Wk,
                         const float* __restrict__ Wv, const float* __restrict__ Wo,
                         const float* __restrict__ W1, const float* __restrict__ W2,
                         bf16* __restrict__ WqkvT, bf16* __restrict__ WoT,
                         bf16* __restrict__ W1T, bf16* __restrict__ W2T) {
  int idx = blockIdx.x * 256 + threadIdx.x;
  if (idx < 3072 * 128) {
    int n = idx >> 7, kk = idx & 127;
    int sel = n >> 10, nn = n & 1023;
    const float* W = (sel == 0) ? Wq : (sel == 1 ? Wk : Wv);
    WqkvT[idx] = (bf16)W[kk * 1024 + nn];
    return;
  }
  int j = idx - 3072 * 128;
  if (j < 128 * 1024) { int n = j >> 10, kk = j & 1023; WoT[j] = (bf16)Wo[kk * 128 + n]; return; }
  j -= 128 * 1024;
  if (j < 16384) { int n = j >> 7, kk = j & 127; W1T[j] = (bf16)W1[kk * 128 + n]; return; }
  j -= 16384;
  if (j < 16384) { int n = j >> 7, kk = j & 127; W2T[j] = (bf16)W2[kk * 128 + n]; return; }
}

// ---------------- QKV projection GEMM: (4096x128)@(128x3072) ----------------
// q,k written [b][h][s][d] (q pre-scaled by 1/sqrt(D)); v written transposed [b][h][d][s].
__global__ __launch_bounds__(256, 4) void k_qkv(
    const bf16* __restrict__ xb, const bf16* __restrict__ WqkvT,
    const float* __restrict__ bq, const float* __restrict__ bk, const float* __restrict__ bv,
    bf16* __restrict__ qT, bf16* __restrict__ kT, bf16* __restrict__ vT) {
  const int bid = blockIdx.x;
  const int m0 = (bid & 63) << 6;
  const int n0 = (bid >> 6) << 6;
  const int tid = threadIdx.x;
  const int w = tid >> 6, lane = tid & 63, lo = lane & 15, hi = lane >> 4;
  const int mw = m0 + ((w >> 1) << 5);
  const int nw = n0 + ((w & 1) << 5);
  bf16x8 av[2][4], bw[2][4];
#pragma unroll
  for (int ms = 0; ms < 2; ++ms)
#pragma unroll
    for (int ks = 0; ks < 4; ++ks)
      av[ms][ks] = ld8(xb + (size_t)(mw + ms * 16 + lo) * 128 + ks * 32 + hi * 8);
#pragma unroll
  for (int ns = 0; ns < 2; ++ns)
#pragma unroll
    for (int ks = 0; ks < 4; ++ks)
      bw[ns][ks] = ld8(WqkvT + (size_t)(nw + ns * 16 + lo) * 128 + ks * 32 + hi * 8);
  const f32x4 z4 = {0.f, 0.f, 0.f, 0.f};
  f32x4 acc[2][2] = {{z4, z4}, {z4, z4}};
#pragma unroll
  for (int ms = 0; ms < 2; ++ms)
#pragma unroll
    for (int ns = 0; ns < 2; ++ns)
#pragma unroll
      for (int ks = 0; ks < 4; ++ks)
        acc[ms][ns] = mfma16(av[ms][ks], bw[ns][ks], acc[ms][ns]);
#pragma unroll
  for (int ns = 0; ns < 2; ++ns) {
    const int n = nw + ns * 16 + lo;
    const int sel = n >> 10, nn = n & 1023;
    const float bia = (sel == 0 ? bq : sel == 1 ? bk : bv)[nn];
    const int hh = nn >> 7, d = nn & 127;
#pragma unroll
    for (int ms = 0; ms < 2; ++ms) {
      const int mb = mw + ms * 16 + hi * 4;
      const int bb = mb >> 11, s = mb & 2047;
      if (sel == 0) {
#pragma unroll
        for (int r = 0; r < 4; ++r)
          qT[(size_t)((bb * 8 + hh) * 2048 + s + r) * 128 + d] =
              (bf16)((acc[ms][ns][r] + bia) * RSQRT_D);
      } else if (sel == 1) {
#pragma unroll
        for (int r = 0; r < 4; ++r)
          kT[(size_t)((bb * 8 + hh) * 2048 + s + r) * 128 + d] = (bf16)(acc[ms][ns][r] + bia);
      } else {
        ushort4 pk;
        pk.x = bfu(acc[ms][ns][0] + bia);
        pk.y = bfu(acc[ms][ns][1] + bia);
        pk.z = bfu(acc[ms][ns][2] + bia);
        pk.w = bfu(acc[ms][ns][3] + bia);
        *(ushort4*)(vT + (size_t)((bb * 8 + hh) * 128 + d) * 2048 + s) = pk;
      }
    }
  }
}

// ---------------- fused attention (v7: r1 structure, 16 waves/block) ----------------
// grid 1024 = 16 (b,h) x 64 q-tiles of 32 rows; 1024 threads = 16 waves; wave w owns kv
// slice [w*128,(w+1)*128) for both q-subtiles (r1's per-wave load economy, 2x the waves).
// Unnormalized P~ bf16 in the 128KB LDS stash (row-XOR swizzle), PV from stash (proven r1
// pattern). Phase 2 writes normalized attn as f32x4 NONTEMPORAL (vs r1's scalar 4B stores).
// XCD-bijective swizzle pins each XCD's 2 (b,h) K/V pairs (2MB) in its 4MB L2.
__global__ __launch_bounds__(1024) __attribute__((amdgpu_waves_per_eu(3, 4))) void k_attn(
    const bf16* __restrict__ qT, const bf16* __restrict__ kT,
    const bf16* __restrict__ vT, const unsigned char* __restrict__ mask8,
    float* __restrict__ attn_out, bf16* __restrict__ Oc) {
  extern __shared__ char smem[];             // [0,128K): P~ stash / Op union; red 2K; red2 128B
  float* red  = (float*)(smem + 131072);
  float* red2 = (float*)(smem + 133120);

  // XCD-aware bijective swizzle: XCD x gets 128 consecutive works = exactly 2 (b,h) pairs.
  const int lbid = blockIdx.x;
  const int work = ((lbid & 7) << 7) + (lbid >> 3);
  const int bh = work >> 6;
  const int q0 = (work & 63) << 5;
  const int b = bh >> 3, h = bh & 7;
  const int tid = threadIdx.x;
  const int w = tid >> 6, lane = tid & 63, lo = lane & 15, hi = lane >> 4;
  const int kv0 = w * 128;

  const bf16* Qh = qT + (size_t)bh * SQ * HD;
  const bf16* Kh = kT + (size_t)bh * SQ * HD;
  const bf16* Vh = vT + (size_t)bh * HD * SQ;

  bf16x8 qf[2][4];                           // 32 q rows (pre-scaled by 1/sqrt(D))
#pragma unroll
  for (int qs = 0; qs < 2; ++qs)
#pragma unroll
    for (int ks = 0; ks < 4; ++ks)
      qf[qs][ks] = ld8(Qh + (size_t)(q0 + qs * 16 + lo) * HD + ks * 32 + hi * 8);

  const f32x4 z4 = {0.f, 0.f, 0.f, 0.f};
  f32x4 acc[2][8];
#pragma unroll
  for (int qs = 0; qs < 2; ++qs)
#pragma unroll
    for (int ds = 0; ds < 8; ++ds) acc[qs][ds] = z4;

  float ssum0 = 0.f, ssum1 = 0.f;

  for (int it = 0; it < 4; ++it) {
    const int kvA = kv0 + it * 32;
    // ---- QK^T (swapped: A=K so D rows are kv, cols are q), mask, exp, stash P~ ----
#pragma unroll
    for (int t = 0; t < 2; ++t) {
      const int kvt = kvA + t * 16;
      bf16x8 af[4];
#pragma unroll
      for (int ks = 0; ks < 4; ++ks)
        af[ks] = ld8(Kh + (size_t)(kvt + lo) * HD + ks * 32 + hi * 8);
#pragma unroll
      for (int qs = 0; qs < 2; ++qs) {
        f32x4 c = z4;
#pragma unroll
        for (int ks = 0; ks < 4; ++ks) c = mfma16(af[ks], qf[qs][ks], c);
        const int qg = q0 + qs * 16 + lo;
        const unsigned mu = *(const unsigned*)(mask8 + (size_t)qg * SQ + kvt + hi * 4);
        float p0 = __expf(c[0] * (0.5f + 0.5f * (float)(mu & 0xff)));
        float p1 = __expf(c[1] * (0.5f + 0.5f * (float)((mu >> 8) & 0xff)));
        float p2 = __expf(c[2] * (0.5f + 0.5f * (float)((mu >> 16) & 0xff)));
        float p3 = __expf(c[3] * (0.5f + 0.5f * (float)((mu >> 24) & 0xff)));
        const float ls = (p0 + p1) + (p2 + p3);
        if (qs == 0) ssum0 += ls; else ssum1 += ls;
        const int row = qs * 16 + lo;
        const unsigned sw = (unsigned)(row & 7) << 4;
        const unsigned byte0 = ((unsigned)row << 12) + (unsigned)(kvt + hi * 4) * 2;
        uint2 pk; pk.x = packbf2(p0, p1); pk.y = packbf2(p2, p3);
        *(uint2*)(smem + (byte0 ^ sw)) = pk;
      }
    }
    // ---- PV over these 32 kv ----
    bf16x8 vf[8];
#pragma unroll
    for (int ds = 0; ds < 8; ++ds)
      vf[ds] = ld8(Vh + (size_t)(ds * 16 + lo) * SQ + kvA + hi * 8);
#pragma unroll
    for (int qs = 0; qs < 2; ++qs) {
      const int row = qs * 16 + lo;
      const unsigned sw = (unsigned)(row & 7) << 4;
      const unsigned byteA = ((unsigned)row << 12) + (unsigned)kvA * 2 + (unsigned)hi * 16;
      bf16x8 pa = *(const bf16x8*)(smem + (byteA ^ sw));
#pragma unroll
      for (int ds = 0; ds < 8; ++ds) acc[qs][ds] = mfma16(pa, vf[ds], acc[qs][ds]);
    }
  }

  // ---- softmax denominators (cross-hi then cross-wave) ----
  ssum0 += __shfl_xor(ssum0, 16); ssum0 += __shfl_xor(ssum0, 32);
  ssum1 += __shfl_xor(ssum1, 16); ssum1 += __shfl_xor(ssum1, 32);
  if (hi == 0) { red[w * 32 + lo] = ssum0; red[w * 32 + 16 + lo] = ssum1; }
  __syncthreads();
  if (tid < 32) {
    float t = 0.f;
#pragma unroll
    for (int ww = 0; ww < 16; ++ww) t += red[ww * 32 + tid];
    red2[tid] = 1.0f / t;
  }
  __syncthreads();

  // ---- phase 2: normalized attention, vectorized f32x4 nontemporal stores ----
  float* abase = attn_out + (size_t)bh * SQ * SQ + (size_t)q0 * SQ;
  for (int it2 = 0; it2 < 16; ++it2) {
    const int seg = it2 * 16 + w;            // 256 segments = 32 rows x 8 parts
    const int row = seg >> 3, part = seg & 7;
    const unsigned sw = (unsigned)(row & 7) << 4;
    const unsigned byte0 = ((unsigned)row << 12) + (unsigned)part * 512 + (unsigned)lane * 8;
    const uint2 pv = *(const uint2*)(smem + (byte0 ^ sw));
    const float rinv = red2[row];
    f32x4 o;
    o[0] = bflo(pv.x) * rinv; o[1] = bfhi(pv.x) * rinv;
    o[2] = bflo(pv.y) * rinv; o[3] = bfhi(pv.y) * rinv;
    __builtin_nontemporal_store(
        o, (f32x4*)(abase + (size_t)row * SQ + part * 256 + lane * 4));
  }
  __syncthreads();

  // ---- cross-wave O reduction in 4 d-chunks of 32 (reuses stash LDS region) ----
  float* Op = (float*)smem;                  // [16 waves][32 q][32 d] f32 per chunk
  for (int dc = 0; dc < 4; ++dc) {
#pragma unroll
    for (int qs = 0; qs < 2; ++qs)
#pragma unroll
      for (int dsl = 0; dsl < 2; ++dsl)
#pragma unroll
        for (int r = 0; r < 4; ++r)
          Op[w * 1024 + (qs * 16 + hi * 4 + r) * 32 + dsl * 16 + lo] =
              acc[qs][dc * 2 + dsl][r];
    __syncthreads();
    const int q = tid >> 5, d = tid & 31;    // 1024 threads = 32q x 32d
    float s = 0.f;
#pragma unroll
    for (int ww = 0; ww < 16; ++ww) s += Op[ww * 1024 + q * 32 + d];
    Oc[(size_t)(b * SQ + q0 + q) * (NH * HD) + h * HD + dc * 32 + d] = (bf16)(s * red2[q]);
    __syncthreads();
  }
}

// ---------------- out@Wo + bo + x -> LayerNorm1 -> h (f32 + bf16) ----------------
__global__ __launch_bounds__(256, 4) void k_owo(
    const bf16* __restrict__ Oc, const bf16* __restrict__ WoT,
    const float* __restrict__ bo, const float* __restrict__ x,
    const float* __restrict__ g1, const float* __restrict__ be1,
    float* __restrict__ hf, bf16* __restrict__ hb) {
  __shared__ __align__(16) float hbuf[16 * 128];
  const int m0 = blockIdx.x * 16;
  const int tid = threadIdx.x;
  const int w = tid >> 6, lane = tid & 63, lo = lane & 15, hi = lane >> 4;
  const int nw = w * 32;
  const f32x4 z4 = {0.f, 0.f, 0.f, 0.f};
  f32x4 acc[2] = {z4, z4};
#pragma unroll 4
  for (int kk = 0; kk < 32; ++kk) {
    bf16x8 a = ld8(Oc + (size_t)(m0 + lo) * 1024 + kk * 32 + hi * 8);
#pragma unroll
    for (int ns = 0; ns < 2; ++ns) {
      bf16x8 bb = ld8(WoT + (size_t)(nw + ns * 16 + lo) * 1024 + kk * 32 + hi * 8);
      acc[ns] = mfma16(a, bb, acc[ns]);
    }
  }
#pragma unroll
  for (int ns = 0; ns < 2; ++ns) {
    const int n = nw + ns * 16 + lo;
    const float bia = bo[n];
#pragma unroll
    for (int r = 0; r < 4; ++r) {
      const int mr = hi * 4 + r;
      hbuf[mr * 128 + n] = acc[ns][r] + bia + x[(size_t)(m0 + mr) * 128 + n];
    }
  }
  __syncthreads();
  const float2 g = *(const float2*)(g1 + lane * 2);
  const float2 be = *(const float2*)(be1 + lane * 2);
#pragma unroll
  for (int rr = 0; rr < 4; ++rr) {
    const int row = w * 4 + rr;
    float2 v = *(float2*)&hbuf[row * 128 + lane * 2];
    float s = v.x + v.y, sq = v.x * v.x + v.y * v.y;
#pragma unroll
    for (int off = 32; off; off >>= 1) { s += __shfl_xor(s, off); sq += __shfl_xor(sq, off); }
    const float mean = s * (1.f / 128.f);
    const float var = sq * (1.f / 128.f) - mean * mean;
    const float rstd = rsqrtf(var + 1e-5f);
    const float y0 = (v.x - mean) * rstd * g.x + be.x;
    const float y1 = (v.y - mean) * rstd * g.y + be.y;
    const size_t o = (size_t)(m0 + row) * 128 + lane * 2;
    *(float2*)(hf + o) = make_float2(y0, y1);
    *(unsigned*)(hb + o) = packbf2(y0, y1);
  }
}

// ---------------- FFN (relu(h@W1+b1)@W2+b2) + residual -> LayerNorm2 -> y ----------------
__global__ __launch_bounds__(256, 4) void k_ffn(
    const bf16* __restrict__ hb, const float* __restrict__ hf,
    const bf16* __restrict__ W1T, const bf16* __restrict__ W2T,
    const float* __restrict__ b1, const float* __restrict__ b2,
    const float* __restrict__ g2, const float* __restrict__ be2,
    float* __restrict__ yout) {
  __shared__ __align__(16) bf16 s1[16 * 136];   // +8 pad per row: conflict-free b128 rereads
  __shared__ __align__(16) float ybuf[16 * 128];
  const int m0 = blockIdx.x * 16;
  const int tid = threadIdx.x;
  const int w = tid >> 6, lane = tid & 63, lo = lane & 15, hi = lane >> 4;
  const int nw = w * 32;
  const f32x4 z4 = {0.f, 0.f, 0.f, 0.f};
  f32x4 a1[2] = {z4, z4};
#pragma unroll
  for (int kk = 0; kk < 4; ++kk) {
    bf16x8 a = ld8(hb + (size_t)(m0 + lo) * 128 + kk * 32 + hi * 8);
#pragma unroll
    for (int ns = 0; ns < 2; ++ns)
      a1[ns] = mfma16(a, ld8(W1T + (size_t)(nw + ns * 16 + lo) * 128 + kk * 32 + hi * 8), a1[ns]);
  }
#pragma unroll
  for (int ns = 0; ns < 2; ++ns) {
    const int n = nw + ns * 16 + lo;
    const float bia = b1[n];
#pragma unroll
    for (int r = 0; r < 4; ++r)
      s1[(hi * 4 + r) * 136 + n] = (bf16)fmaxf(a1[ns][r] + bia, 0.f);
  }
  __syncthreads();
  f32x4 a2[2] = {z4, z4};
#pragma unroll
  for (int kk = 0; kk < 4; ++kk) {
    bf16x8 a = *(const bf16x8*)&s1[lo * 136 + kk * 32 + hi * 8];
#pragma unroll
    for (int ns = 0; ns < 2; ++ns)
      a2[ns] = mfma16(a, ld8(W2T + (size_t)(nw + ns * 16 + lo) * 128 + kk * 32 + hi * 8), a2[ns]);
  }
#pragma unroll
  for (int ns = 0; ns < 2; ++ns) {
    const int n = nw + ns * 16 + lo;
    const float bia = b2[n];
#pragma unroll
    for (int r = 0; r < 4; ++r) {
      const int mr = hi * 4 + r;
      ybuf[mr * 128 + n] = a2[ns][r] + bia + hf[(size_t)(m0 + mr) * 128 + n];
    }
  }
  __syncthreads();
  const float2 g = *(const float2*)(g2 + lane * 2);
  const float2 be = *(const float2*)(be2 + lane * 2);
#pragma unroll
  for (int rr = 0; rr < 4; ++rr) {
    const int row = w * 4 + rr;
    float2 v = *(float2*)&ybuf[row * 128 + lane * 2];
    float s = v.x + v.y, sq = v.x * v.x + v.y * v.y;
#pragma unroll
    for (int off = 32; off; off >>= 1) { s += __shfl_xor(s, off); sq += __shfl_xor(sq, off); }
    const float mean = s * (1.f / 128.f);
    const float var = sq * (1.f / 128.f) - mean * mean;
    const float rstd = rsqrtf(var + 1e-5f);
    const float y0 = (v.x - mean) * rstd * g.x + be.x;
    const float y1 = (v.y - mean) * rstd * g.y + be.y;
    *(float2*)(yout + (size_t)(m0 + row) * 128 + lane * 2) = make_float2(y0, y1);
  }
}

extern "C" void kernel_launch(void* const* d_in, const int* in_sizes, int n_in,
                              void* d_out, int out_size, void* d_ws, size_t ws_size,
                              hipStream_t stream) {
  const float* x  = (const float*)d_in[0];
  const int* adj  = (const int*)d_in[1];
  const float* Wq = (const float*)d_in[2];  const float* bq = (const float*)d_in[3];
  const float* Wk = (const float*)d_in[4];  const float* bk = (const float*)d_in[5];
  const float* Wv = (const float*)d_in[6];  const float* bv = (const float*)d_in[7];
  const float* Wo = (const float*)d_in[8];  const float* bo = (const float*)d_in[9];
  const float* g1 = (const float*)d_in[10]; const float* be1 = (const float*)d_in[11];
  const float* g2 = (const float*)d_in[12]; const float* be2 = (const float*)d_in[13];
  const float* W1 = (const float*)d_in[14]; const float* b1 = (const float*)d_in[15];
  const float* W2 = (const float*)d_in[16]; const float* b2 = (const float*)d_in[17];

  char* ws = (char*)d_ws;
  bf16* xb     = (bf16*)(ws + 0);
  bf16* WqkvT  = (bf16*)(ws + 1048576);
  bf16* WoT    = (bf16*)(ws + 1835008);
  bf16* W1T    = (bf16*)(ws + 2097152);
  bf16* W2T    = (bf16*)(ws + 2129920);
  unsigned char* mask8 = (unsigned char*)(ws + 2162688);
  bf16* qT     = (bf16*)(ws + 6356992);
  bf16* kT     = (bf16*)(ws + 14745600);
  bf16* vT     = (bf16*)(ws + 23134208);
  bf16* Oc     = (bf16*)(ws + 31522816);
  float* hf    = (float*)(ws + 39911424);
  bf16* hb     = (bf16*)(ws + 42008576);

  float* yout = (float*)d_out;
  float* attn_out = yout + (size_t)NROWS * HD;  // y first (524288 f32), then attn

  hipFuncSetAttribute((const void*)k_attn, hipFuncAttributeMaxDynamicSharedMemorySize, 133248);

  k_prep_a<<<6144, 256, 0, stream>>>(x, adj, xb, mask8);
  k_prep_w<<<2176, 256, 0, stream>>>(Wq, Wk, Wv, Wo, W1, W2, WqkvT, WoT, W1T, W2T);
  k_qkv<<<3072, 256, 0, stream>>>(xb, WqkvT, bq, bk, bv, qT, kT, vT);
  k_attn<<<1024, 1024, 133248, stream>>>(qT, kT, vT, mask8, attn_out, Oc);
  k_owo<<<256, 256, 0, stream>>>(Oc, WoT, bo, x, g1, be1, hf, hb);
  k_ffn<<<256, 256, 0, stream>>>(hb, hf, W1T, W2T, b1, b2, g2, be2, yout);
}

// Round 9
// 260.161 us; speedup vs baseline: 1.5120x; 1.5120x over previous
//
#include <hip/hip_runtime.h>
#include <hip/hip_bf16.h>

// ---- problem constants ----
#define HD 128          // head dim == hidden dim
#define NH 8            // heads
#define SQ 2048         // seq len
#define NROWS 4096      // B*S
#define RSQRT_D 0.08838834764831845f

typedef __bf16 bf16;
typedef bf16 bf16x8 __attribute__((ext_vector_type(8)));
typedef float f32x4 __attribute__((ext_vector_type(4)));

__device__ __forceinline__ f32x4 mfma16(bf16x8 a, bf16x8 b, f32x4 c) {
  return __builtin_amdgcn_mfma_f32_16x16x32_bf16(a, b, c, 0, 0, 0);
}
__device__ __forceinline__ bf16x8 ld8(const bf16* p) { return *(const bf16x8*)p; }
__device__ __forceinline__ unsigned short bfu(float v) {
  return __builtin_bit_cast(unsigned short, (bf16)v);
}
__device__ __forceinline__ unsigned packbf2(float a, float b) {
  return (unsigned)bfu(a) | ((unsigned)bfu(b) << 16);
}
__device__ __forceinline__ float bflo(unsigned u) {
  return __builtin_bit_cast(float, u << 16);
}
__device__ __forceinline__ float bfhi(unsigned u) {
  return __builtin_bit_cast(float, u & 0xffff0000u);
}

// ---------------- prep: x->bf16, adj->u8 ----------------
__global__ void k_prep_a(const float* __restrict__ x, const int* __restrict__ adj,
                         bf16* __restrict__ xb, unsigned char* __restrict__ mask8) {
  int idx = blockIdx.x * 256 + threadIdx.x;
  if (idx < NROWS * HD) { xb[idx] = (bf16)x[idx]; return; }
  int j = idx - NROWS * HD;
  if (j < (SQ * SQ / 4)) {
    int4 a = ((const int4*)adj)[j];
    uchar4 m;
    m.x = (unsigned char)a.x; m.y = (unsigned char)a.y;
    m.z = (unsigned char)a.z; m.w = (unsigned char)a.w;
    ((uchar4*)mask8)[j] = m;
  }
}

// ---------------- prep: weights -> bf16, [n][k] layout ----------------
__global__ void k_prep_w(const float* __restrict__ Wq, const float* __restrict__ Wk,
                         const float* __restrict__ Wv, const float* __restrict__ Wo,
                         const float* __restrict__ W1, const float* __restrict__ W2,
                         bf16* __restrict__ WqkvT, bf16* __restrict__ WoT,
                         bf16* __restrict__ W1T, bf16* __restrict__ W2T) {
  int idx = blockIdx.x * 256 + threadIdx.x;
  if (idx < 3072 * 128) {
    int n = idx >> 7, kk = idx & 127;
    int sel = n >> 10, nn = n & 1023;
    const float* W = (sel == 0) ? Wq : (sel == 1 ? Wk : Wv);
    WqkvT[idx] = (bf16)W[kk * 1024 + nn];
    return;
  }
  int j = idx - 3072 * 128;
  if (j < 128 * 1024) { int n = j >> 10, kk = j & 1023; WoT[j] = (bf16)Wo[kk * 128 + n]; return; }
  j -= 128 * 1024;
  if (j < 16384) { int n = j >> 7, kk = j & 127; W1T[j] = (bf16)W1[kk * 128 + n]; return; }
  j -= 16384;
  if (j < 16384) { int n = j >> 7, kk = j & 127; W2T[j] = (bf16)W2[kk * 128 + n]; return; }
}

// ---------------- QKV projection GEMM: (4096x128)@(128x3072) ----------------
// q,k written [b][h][s][d] (q pre-scaled by 1/sqrt(D)); v written transposed [b][h][d][s].
__global__ __launch_bounds__(256, 4) void k_qkv(
    const bf16* __restrict__ xb, const bf16* __restrict__ WqkvT,
    const float* __restrict__ bq, const float* __restrict__ bk, const float* __restrict__ bv,
    bf16* __restrict__ qT, bf16* __restrict__ kT, bf16* __restrict__ vT) {
  const int bid = blockIdx.x;
  const int m0 = (bid & 63) << 6;
  const int n0 = (bid >> 6) << 6;
  const int tid = threadIdx.x;
  const int w = tid >> 6, lane = tid & 63, lo = lane & 15, hi = lane >> 4;
  const int mw = m0 + ((w >> 1) << 5);
  const int nw = n0 + ((w & 1) << 5);
  bf16x8 av[2][4], bw[2][4];
#pragma unroll
  for (int ms = 0; ms < 2; ++ms)
#pragma unroll
    for (int ks = 0; ks < 4; ++ks)
      av[ms][ks] = ld8(xb + (size_t)(mw + ms * 16 + lo) * 128 + ks * 32 + hi * 8);
#pragma unroll
  for (int ns = 0; ns < 2; ++ns)
#pragma unroll
    for (int ks = 0; ks < 4; ++ks)
      bw[ns][ks] = ld8(WqkvT + (size_t)(nw + ns * 16 + lo) * 128 + ks * 32 + hi * 8);
  const f32x4 z4 = {0.f, 0.f, 0.f, 0.f};
  f32x4 acc[2][2] = {{z4, z4}, {z4, z4}};
#pragma unroll
  for (int ms = 0; ms < 2; ++ms)
#pragma unroll
    for (int ns = 0; ns < 2; ++ns)
#pragma unroll
      for (int ks = 0; ks < 4; ++ks)
        acc[ms][ns] = mfma16(av[ms][ks], bw[ns][ks], acc[ms][ns]);
#pragma unroll
  for (int ns = 0; ns < 2; ++ns) {
    const int n = nw + ns * 16 + lo;
    const int sel = n >> 10, nn = n & 1023;
    const float bia = (sel == 0 ? bq : sel == 1 ? bk : bv)[nn];
    const int hh = nn >> 7, d = nn & 127;
#pragma unroll
    for (int ms = 0; ms < 2; ++ms) {
      const int mb = mw + ms * 16 + hi * 4;
      const int bb = mb >> 11, s = mb & 2047;
      if (sel == 0) {
#pragma unroll
        for (int r = 0; r < 4; ++r)
          qT[(size_t)((bb * 8 + hh) * 2048 + s + r) * 128 + d] =
              (bf16)((acc[ms][ns][r] + bia) * RSQRT_D);
      } else if (sel == 1) {
#pragma unroll
        for (int r = 0; r < 4; ++r)
          kT[(size_t)((bb * 8 + hh) * 2048 + s + r) * 128 + d] = (bf16)(acc[ms][ns][r] + bia);
      } else {
        ushort4 pk;
        pk.x = bfu(acc[ms][ns][0] + bia);
        pk.y = bfu(acc[ms][ns][1] + bia);
        pk.z = bfu(acc[ms][ns][2] + bia);
        pk.w = bfu(acc[ms][ns][3] + bia);
        *(ushort4*)(vT + (size_t)((bb * 8 + hh) * 128 + d) * 2048 + s) = pk;
      }
    }
  }
}

// ---------------- fused attention (v8 = r1 structure + XCD swizzle + vector phase-2) ----
// grid 1024 = 16 (b,h) x 64 q-tiles of 32 rows. 512 threads = 8 waves (2/SIMD -> 256-reg
// budget, the proven no-spill point), wave w owns kv slice [w*256,(w+1)*256).
// Unnormalized P~=exp(score*mask) bf16 in the 128KB LDS stash (row-XOR swizzle); PV reads
// A-frags back with the SAME k-map as V's B-frags. Phase 2: normalized attn written as
// f32x4 NONTEMPORAL (1KB/wave-inst, r1 did 4B scalar). XCD-bijective swizzle pins each
// XCD's 2 (b,h) K/V pairs (2MB) in its private 4MB L2.
__global__ __launch_bounds__(512, 2) void k_attn(
    const bf16* __restrict__ qT, const bf16* __restrict__ kT,
    const bf16* __restrict__ vT, const unsigned char* __restrict__ mask8,
    float* __restrict__ attn_out, bf16* __restrict__ Oc) {
  extern __shared__ char smem[];             // [32][2048] bf16 P~ (128KB) + 1152B reductions
  float* red = (float*)(smem + 131072);

  // XCD-aware bijective swizzle: XCD x gets 128 consecutive works = exactly 2 (b,h) pairs.
  const int lbid = blockIdx.x;
  const int work = ((lbid & 7) << 7) + (lbid >> 3);
  const int bh = work >> 6;
  const int q0 = (work & 63) << 5;
  const int b = bh >> 3, h = bh & 7;
  const int tid = threadIdx.x;
  const int w = tid >> 6, lane = tid & 63, lo = lane & 15, hi = lane >> 4;

  const bf16* Qh = qT + (size_t)bh * SQ * HD;
  const bf16* Kh = kT + (size_t)bh * SQ * HD;
  const bf16* Vh = vT + (size_t)bh * HD * SQ;

  bf16x8 qf[2][4];                           // hoist Q tile (already scaled by 1/sqrt(D))
#pragma unroll
  for (int qs = 0; qs < 2; ++qs)
#pragma unroll
    for (int ks = 0; ks < 4; ++ks)
      qf[qs][ks] = ld8(Qh + (size_t)(q0 + qs * 16 + lo) * HD + ks * 32 + hi * 8);

  const f32x4 z4 = {0.f, 0.f, 0.f, 0.f};
  f32x4 acc[2][8];
#pragma unroll
  for (int qs = 0; qs < 2; ++qs)
#pragma unroll
    for (int ds = 0; ds < 8; ++ds) acc[qs][ds] = z4;

  float ssum0 = 0.f, ssum1 = 0.f;
  const int kvbase = w * 256;

  for (int it = 0; it < 8; ++it) {
    const int kvA = kvbase + it * 32;
    // ---- QK^T (swapped: A=K so D rows are kv, cols are q), mask, exp, stash P~ ----
#pragma unroll
    for (int t = 0; t < 2; ++t) {
      const int kvt = kvA + t * 16;
      bf16x8 af[4];
#pragma unroll
      for (int ks = 0; ks < 4; ++ks)
        af[ks] = ld8(Kh + (size_t)(kvt + lo) * HD + ks * 32 + hi * 8);
#pragma unroll
      for (int qs = 0; qs < 2; ++qs) {
        f32x4 c = z4;
#pragma unroll
        for (int ks = 0; ks < 4; ++ks) c = mfma16(af[ks], qf[qs][ks], c);
        const int qg = q0 + qs * 16 + lo;
        const unsigned mu = *(const unsigned*)(mask8 + (size_t)qg * SQ + kvt + hi * 4);
        float p0 = __expf(c[0] * (0.5f + 0.5f * (float)(mu & 0xff)));
        float p1 = __expf(c[1] * (0.5f + 0.5f * (float)((mu >> 8) & 0xff)));
        float p2 = __expf(c[2] * (0.5f + 0.5f * (float)((mu >> 16) & 0xff)));
        float p3 = __expf(c[3] * (0.5f + 0.5f * (float)((mu >> 24) & 0xff)));
        const float ls = (p0 + p1) + (p2 + p3);
        if (qs == 0) ssum0 += ls; else ssum1 += ls;
        const int row = qs * 16 + lo;
        const unsigned sw = (unsigned)(row & 7) << 4;
        const unsigned byte0 = ((unsigned)row << 12) + (unsigned)(kvt + hi * 4) * 2;
        uint2 pk; pk.x = packbf2(p0, p1); pk.y = packbf2(p2, p3);
        *(uint2*)(smem + (byte0 ^ sw)) = pk;
      }
    }
    // ---- PV over these 32 kv ----
    bf16x8 vf[8];
#pragma unroll
    for (int ds = 0; ds < 8; ++ds)
      vf[ds] = ld8(Vh + (size_t)(ds * 16 + lo) * SQ + kvA + hi * 8);
#pragma unroll
    for (int qs = 0; qs < 2; ++qs) {
      const int row = qs * 16 + lo;
      const unsigned sw = (unsigned)(row & 7) << 4;
      const unsigned byteA = ((unsigned)row << 12) + (unsigned)kvA * 2 + (unsigned)hi * 16;
      bf16x8 pa = *(const bf16x8*)(smem + (byteA ^ sw));
#pragma unroll
      for (int ds = 0; ds < 8; ++ds) acc[qs][ds] = mfma16(pa, vf[ds], acc[qs][ds]);
    }
  }

  // ---- softmax denominators (cross-hi then cross-wave) ----
  ssum0 += __shfl_xor(ssum0, 16); ssum0 += __shfl_xor(ssum0, 32);
  ssum1 += __shfl_xor(ssum1, 16); ssum1 += __shfl_xor(ssum1, 32);
  if (hi == 0) { red[w * 32 + lo] = ssum0; red[w * 32 + 16 + lo] = ssum1; }
  __syncthreads();
  if (tid < 32) {
    float t = 0.f;
#pragma unroll
    for (int ww = 0; ww < 8; ++ww) t += red[ww * 32 + tid];
    red[256 + tid] = 1.0f / t;
  }
  __syncthreads();

  // ---- phase 2: normalized attention, vectorized f32x4 nontemporal stores ----
  float* abase = attn_out + (size_t)bh * SQ * SQ + (size_t)q0 * SQ;
#pragma unroll 4
  for (int it2 = 0; it2 < 32; ++it2) {
    const int seg = it2 * 8 + w;             // 256 segments = 32 rows x 8 parts
    const int row = seg >> 3, part = seg & 7;
    const unsigned sw = (unsigned)(row & 7) << 4;
    const unsigned byte0 = ((unsigned)row << 12) + (unsigned)part * 512 + (unsigned)lane * 8;
    const uint2 pv = *(const uint2*)(smem + (byte0 ^ sw));
    const float rinv = red[256 + row];
    f32x4 o;
    o[0] = bflo(pv.x) * rinv; o[1] = bfhi(pv.x) * rinv;
    o[2] = bflo(pv.y) * rinv; o[3] = bfhi(pv.y) * rinv;
    __builtin_nontemporal_store(
        o, (f32x4*)(abase + (size_t)row * SQ + part * 256 + lane * 4));
  }
  __syncthreads();

  // ---- cross-wave O reduction (reuse P~ LDS) ----
  float* Op = (float*)smem;  // [8][32][128]
#pragma unroll
  for (int qs = 0; qs < 2; ++qs)
#pragma unroll
    for (int ds = 0; ds < 8; ++ds)
#pragma unroll
      for (int r = 0; r < 4; ++r)
        Op[(w * 32 + qs * 16 + hi * 4 + r) * 128 + ds * 16 + lo] = acc[qs][ds][r];
  __syncthreads();
  for (int e = tid; e < 32 * 128; e += 512) {
    const int q = e >> 7, d = e & 127;
    float s = 0.f;
#pragma unroll
    for (int ww = 0; ww < 8; ++ww) s += Op[ww * 4096 + e];
    Oc[(size_t)(b * SQ + q0 + q) * (NH * HD) + h * HD + d] = (bf16)(s * red[256 + q]);
  }
}

// ---------------- out@Wo + bo + x -> LayerNorm1 -> h (f32 + bf16) ----------------
__global__ __launch_bounds__(256, 4) void k_owo(
    const bf16* __restrict__ Oc, const bf16* __restrict__ WoT,
    const float* __restrict__ bo, const float* __restrict__ x,
    const float* __restrict__ g1, const float* __restrict__ be1,
    float* __restrict__ hf, bf16* __restrict__ hb) {
  __shared__ __align__(16) float hbuf[16 * 128];
  const int m0 = blockIdx.x * 16;
  const int tid = threadIdx.x;
  const int w = tid >> 6, lane = tid & 63, lo = lane & 15, hi = lane >> 4;
  const int nw = w * 32;
  const f32x4 z4 = {0.f, 0.f, 0.f, 0.f};
  f32x4 acc[2] = {z4, z4};
#pragma unroll 4
  for (int kk = 0; kk < 32; ++kk) {
    bf16x8 a = ld8(Oc + (size_t)(m0 + lo) * 1024 + kk * 32 + hi * 8);
#pragma unroll
    for (int ns = 0; ns < 2; ++ns) {
      bf16x8 bb = ld8(WoT + (size_t)(nw + ns * 16 + lo) * 1024 + kk * 32 + hi * 8);
      acc[ns] = mfma16(a, bb, acc[ns]);
    }
  }
#pragma unroll
  for (int ns = 0; ns < 2; ++ns) {
    const int n = nw + ns * 16 + lo;
    const float bia = bo[n];
#pragma unroll
    for (int r = 0; r < 4; ++r) {
      const int mr = hi * 4 + r;
      hbuf[mr * 128 + n] = acc[ns][r] + bia + x[(size_t)(m0 + mr) * 128 + n];
    }
  }
  __syncthreads();
  const float2 g = *(const float2*)(g1 + lane * 2);
  const float2 be = *(const float2*)(be1 + lane * 2);
#pragma unroll
  for (int rr = 0; rr < 4; ++rr) {
    const int row = w * 4 + rr;
    float2 v = *(float2*)&hbuf[row * 128 + lane * 2];
    float s = v.x + v.y, sq = v.x * v.x + v.y * v.y;
#pragma unroll
    for (int off = 32; off; off >>= 1) { s += __shfl_xor(s, off); sq += __shfl_xor(sq, off); }
    const float mean = s * (1.f / 128.f);
    const float var = sq * (1.f / 128.f) - mean * mean;
    const float rstd = rsqrtf(var + 1e-5f);
    const float y0 = (v.x - mean) * rstd * g.x + be.x;
    const float y1 = (v.y - mean) * rstd * g.y + be.y;
    const size_t o = (size_t)(m0 + row) * 128 + lane * 2;
    *(float2*)(hf + o) = make_float2(y0, y1);
    *(unsigned*)(hb + o) = packbf2(y0, y1);
  }
}

// ---------------- FFN (relu(h@W1+b1)@W2+b2) + residual -> LayerNorm2 -> y ----------------
__global__ __launch_bounds__(256, 4) void k_ffn(
    const bf16* __restrict__ hb, const float* __restrict__ hf,
    const bf16* __restrict__ W1T, const bf16* __restrict__ W2T,
    const float* __restrict__ b1, const float* __restrict__ b2,
    const float* __restrict__ g2, const float* __restrict__ be2,
    float* __restrict__ yout) {
  __shared__ __align__(16) bf16 s1[16 * 136];   // +8 pad per row: conflict-free b128 rereads
  __shared__ __align__(16) float ybuf[16 * 128];
  const int m0 = blockIdx.x * 16;
  const int tid = threadIdx.x;
  const int w = tid >> 6, lane = tid & 63, lo = lane & 15, hi = lane >> 4;
  const int nw = w * 32;
  const f32x4 z4 = {0.f, 0.f, 0.f, 0.f};
  f32x4 a1[2] = {z4, z4};
#pragma unroll
  for (int kk = 0; kk < 4; ++kk) {
    bf16x8 a = ld8(hb + (size_t)(m0 + lo) * 128 + kk * 32 + hi * 8);
#pragma unroll
    for (int ns = 0; ns < 2; ++ns)
      a1[ns] = mfma16(a, ld8(W1T + (size_t)(nw + ns * 16 + lo) * 128 + kk * 32 + hi * 8), a1[ns]);
  }
#pragma unroll
  for (int ns = 0; ns < 2; ++ns) {
    const int n = nw + ns * 16 + lo;
    const float bia = b1[n];
#pragma unroll
    for (int r = 0; r < 4; ++r)
      s1[(hi * 4 + r) * 136 + n] = (bf16)fmaxf(a1[ns][r] + bia, 0.f);
  }
  __syncthreads();
  f32x4 a2[2] = {z4, z4};
#pragma unroll
  for (int kk = 0; kk < 4; ++kk) {
    bf16x8 a = *(const bf16x8*)&s1[lo * 136 + kk * 32 + hi * 8];
#pragma unroll
    for (int ns = 0; ns < 2; ++ns)
      a2[ns] = mfma16(a, ld8(W2T + (size_t)(nw + ns * 16 + lo) * 128 + kk * 32 + hi * 8), a2[ns]);
  }
#pragma unroll
  for (int ns = 0; ns < 2; ++ns) {
    const int n = nw + ns * 16 + lo;
    const float bia = b2[n];
#pragma unroll
    for (int r = 0; r < 4; ++r) {
      const int mr = hi * 4 + r;
      ybuf[mr * 128 + n] = a2[ns][r] + bia + hf[(size_t)(m0 + mr) * 128 + n];
    }
  }
  __syncthreads();
  const float2 g = *(const float2*)(g2 + lane * 2);
  const float2 be = *(const float2*)(be2 + lane * 2);
#pragma unroll
  for (int rr = 0; rr < 4; ++rr) {
    const int row = w * 4 + rr;
    float2 v = *(float2*)&ybuf[row * 128 + lane * 2];
    float s = v.x + v.y, sq = v.x * v.x + v.y * v.y;
#pragma unroll
    for (int off = 32; off; off >>= 1) { s += __shfl_xor(s, off); sq += __shfl_xor(sq, off); }
    const float mean = s * (1.f / 128.f);
    const float var = sq * (1.f / 128.f) - mean * mean;
    const float rstd = rsqrtf(var + 1e-5f);
    const float y0 = (v.x - mean) * rstd * g.x + be.x;
    const float y1 = (v.y - mean) * rstd * g.y + be.y;
    *(float2*)(yout + (size_t)(m0 + row) * 128 + lane * 2) = make_float2(y0, y1);
  }
}

extern "C" void kernel_launch(void* const* d_in, const int* in_sizes, int n_in,
                              void* d_out, int out_size, void* d_ws, size_t ws_size,
                              hipStream_t stream) {
  const float* x  = (const float*)d_in[0];
  const int* adj  = (const int*)d_in[1];
  const float* Wq = (const float*)d_in[2];  const float* bq = (const float*)d_in[3];
  const float* Wk = (const float*)d_in[4];  const float* bk = (const float*)d_in[5];
  const float* Wv = (const float*)d_in[6];  const float* bv = (const float*)d_in[7];
  const float* Wo = (const float*)d_in[8];  const float* bo = (const float*)d_in[9];
  const float* g1 = (const float*)d_in[10]; const float* be1 = (const float*)d_in[11];
  const float* g2 = (const float*)d_in[12]; const float* be2 = (const float*)d_in[13];
  const float* W1 = (const float*)d_in[14]; const float* b1 = (const float*)d_in[15];
  const float* W2 = (const float*)d_in[16]; const float* b2 = (const float*)d_in[17];

  char* ws = (char*)d_ws;
  bf16* xb     = (bf16*)(ws + 0);
  bf16* WqkvT  = (bf16*)(ws + 1048576);
  bf16* WoT    = (bf16*)(ws + 1835008);
  bf16* W1T    = (bf16*)(ws + 2097152);
  bf16* W2T    = (bf16*)(ws + 2129920);
  unsigned char* mask8 = (unsigned char*)(ws + 2162688);
  bf16* qT     = (bf16*)(ws + 6356992);
  bf16* kT     = (bf16*)(ws + 14745600);
  bf16* vT     = (bf16*)(ws + 23134208);
  bf16* Oc     = (bf16*)(ws + 31522816);
  float* hf    = (float*)(ws + 39911424);
  bf16* hb     = (bf16*)(ws + 42008576);

  float* yout = (float*)d_out;
  float* attn_out = yout + (size_t)NROWS * HD;  // y first (524288 f32), then attn

  hipFuncSetAttribute((const void*)k_attn, hipFuncAttributeMaxDynamicSharedMemorySize, 132224);

  k_prep_a<<<6144, 256, 0, stream>>>(x, adj, xb, mask8);
  k_prep_w<<<2176, 256, 0, stream>>>(Wq, Wk, Wv, Wo, W1, W2, WqkvT, WoT, W1T, W2T);
  k_qkv<<<3072, 256, 0, stream>>>(xb, WqkvT, bq, bk, bv, qT, kT, vT);
  k_attn<<<1024, 512, 132224, stream>>>(qT, kT, vT, mask8, attn_out, Oc);
  k_owo<<<256, 256, 0, stream>>>(Oc, WoT, bo, x, g1, be1, hf, hb);
  k_ffn<<<256, 256, 0, stream>>>(hb, hf, W1T, W2T, b1, b2, g2, be2, yout);
}

// Round 10
// 256.712 us; speedup vs baseline: 1.5323x; 1.0134x over previous
//
#include <hip/hip_runtime.h>
#include <hip/hip_bf16.h>

// ---- problem constants ----
#define HD 128          // head dim == hidden dim
#define NH 8            // heads
#define SQ 2048         // seq len
#define NROWS 4096      // B*S
#define RSQRT_D 0.08838834764831845f

typedef __bf16 bf16;
typedef bf16 bf16x8 __attribute__((ext_vector_type(8)));
typedef float f32x4 __attribute__((ext_vector_type(4)));

__device__ __forceinline__ f32x4 mfma16(bf16x8 a, bf16x8 b, f32x4 c) {
  return __builtin_amdgcn_mfma_f32_16x16x32_bf16(a, b, c, 0, 0, 0);
}
__device__ __forceinline__ bf16x8 ld8(const bf16* p) { return *(const bf16x8*)p; }
__device__ __forceinline__ unsigned short bfu(float v) {
  return __builtin_bit_cast(unsigned short, (bf16)v);
}
__device__ __forceinline__ unsigned packbf2(float a, float b) {
  return (unsigned)bfu(a) | ((unsigned)bfu(b) << 16);
}
__device__ __forceinline__ float bflo(unsigned u) {
  return __builtin_bit_cast(float, u << 16);
}
__device__ __forceinline__ float bfhi(unsigned u) {
  return __builtin_bit_cast(float, u & 0xffff0000u);
}

// ---------------- prep: x->bf16, adj->u8 ----------------
__global__ void k_prep_a(const float* __restrict__ x, const int* __restrict__ adj,
                         bf16* __restrict__ xb, unsigned char* __restrict__ mask8) {
  int idx = blockIdx.x * 256 + threadIdx.x;
  if (idx < NROWS * HD) { xb[idx] = (bf16)x[idx]; return; }
  int j = idx - NROWS * HD;
  if (j < (SQ * SQ / 4)) {
    int4 a = ((const int4*)adj)[j];
    uchar4 m;
    m.x = (unsigned char)a.x; m.y = (unsigned char)a.y;
    m.z = (unsigned char)a.z; m.w = (unsigned char)a.w;
    ((uchar4*)mask8)[j] = m;
  }
}

// ---------------- prep: weights -> bf16, [n][k] layout ----------------
__global__ void k_prep_w(const float* __restrict__ Wq, const float* __restrict__ Wk,
                         const float* __restrict__ Wv, const float* __restrict__ Wo,
                         const float* __restrict__ W1, const float* __restrict__ W2,
                         bf16* __restrict__ WqkvT, bf16* __restrict__ WoT,
                         bf16* __restrict__ W1T, bf16* __restrict__ W2T) {
  int idx = blockIdx.x * 256 + threadIdx.x;
  if (idx < 3072 * 128) {
    int n = idx >> 7, kk = idx & 127;
    int sel = n >> 10, nn = n & 1023;
    const float* W = (sel == 0) ? Wq : (sel == 1 ? Wk : Wv);
    WqkvT[idx] = (bf16)W[kk * 1024 + nn];
    return;
  }
  int j = idx - 3072 * 128;
  if (j < 128 * 1024) { int n = j >> 10, kk = j & 1023; WoT[j] = (bf16)Wo[kk * 128 + n]; return; }
  j -= 128 * 1024;
  if (j < 16384) { int n = j >> 7, kk = j & 127; W1T[j] = (bf16)W1[kk * 128 + n]; return; }
  j -= 16384;
  if (j < 16384) { int n = j >> 7, kk = j & 127; W2T[j] = (bf16)W2[kk * 128 + n]; return; }
}

// ---------------- QKV projection GEMM: (4096x128)@(128x3072) ----------------
// q,k written [b][h][s][d] (q pre-scaled by 1/sqrt(D)); v written transposed [b][h][d][s].
__global__ __launch_bounds__(256, 4) void k_qkv(
    const bf16* __restrict__ xb, const bf16* __restrict__ WqkvT,
    const float* __restrict__ bq, const float* __restrict__ bk, const float* __restrict__ bv,
    bf16* __restrict__ qT, bf16* __restrict__ kT, bf16* __restrict__ vT) {
  const int bid = blockIdx.x;
  const int m0 = (bid & 63) << 6;
  const int n0 = (bid >> 6) << 6;
  const int tid = threadIdx.x;
  const int w = tid >> 6, lane = tid & 63, lo = lane & 15, hi = lane >> 4;
  const int mw = m0 + ((w >> 1) << 5);
  const int nw = n0 + ((w & 1) << 5);
  bf16x8 av[2][4], bw[2][4];
#pragma unroll
  for (int ms = 0; ms < 2; ++ms)
#pragma unroll
    for (int ks = 0; ks < 4; ++ks)
      av[ms][ks] = ld8(xb + (size_t)(mw + ms * 16 + lo) * 128 + ks * 32 + hi * 8);
#pragma unroll
  for (int ns = 0; ns < 2; ++ns)
#pragma unroll
    for (int ks = 0; ks < 4; ++ks)
      bw[ns][ks] = ld8(WqkvT + (size_t)(nw + ns * 16 + lo) * 128 + ks * 32 + hi * 8);
  const f32x4 z4 = {0.f, 0.f, 0.f, 0.f};
  f32x4 acc[2][2] = {{z4, z4}, {z4, z4}};
#pragma unroll
  for (int ms = 0; ms < 2; ++ms)
#pragma unroll
    for (int ns = 0; ns < 2; ++ns)
#pragma unroll
      for (int ks = 0; ks < 4; ++ks)
        acc[ms][ns] = mfma16(av[ms][ks], bw[ns][ks], acc[ms][ns]);
#pragma unroll
  for (int ns = 0; ns < 2; ++ns) {
    const int n = nw + ns * 16 + lo;
    const int sel = n >> 10, nn = n & 1023;
    const float bia = (sel == 0 ? bq : sel == 1 ? bk : bv)[nn];
    const int hh = nn >> 7, d = nn & 127;
#pragma unroll
    for (int ms = 0; ms < 2; ++ms) {
      const int mb = mw + ms * 16 + hi * 4;
      const int bb = mb >> 11, s = mb & 2047;
      if (sel == 0) {
#pragma unroll
        for (int r = 0; r < 4; ++r)
          qT[(size_t)((bb * 8 + hh) * 2048 + s + r) * 128 + d] =
              (bf16)((acc[ms][ns][r] + bia) * RSQRT_D);
      } else if (sel == 1) {
#pragma unroll
        for (int r = 0; r < 4; ++r)
          kT[(size_t)((bb * 8 + hh) * 2048 + s + r) * 128 + d] = (bf16)(acc[ms][ns][r] + bia);
      } else {
        ushort4 pk;
        pk.x = bfu(acc[ms][ns][0] + bia);
        pk.y = bfu(acc[ms][ns][1] + bia);
        pk.z = bfu(acc[ms][ns][2] + bia);
        pk.w = bfu(acc[ms][ns][3] + bia);
        *(ushort4*)(vT + (size_t)((bb * 8 + hh) * 128 + d) * 2048 + s) = pk;
      }
    }
  }
}

// ---------------- fused attention (v9 = r9 + forced load-batching via sched_barrier) ----
// grid 1024 = 16 (b,h) x 64 q-tiles of 32 rows. 512 threads = 8 waves (2/SIMD -> 256-reg
// budget), wave w owns kv slice [w*256,(w+1)*256). Per 32-kv iteration ALL 16 K/V loads
// (af0,af1,vf = 128 VGPRs in flight) are issued up front, then sched_barrier(0) pins them
// above the compute: 3 serial latency episodes/iter -> 1. Counted vmcnt waits mean t0's
// MFMA only waits on af0. s_setprio(1) wraps the PV MFMA cluster (independent waves ->
// T5-positive regime). Phase 2: f32x4 nontemporal attn writes. XCD-bijective swizzle.
__global__ __launch_bounds__(512, 2) void k_attn(
    const bf16* __restrict__ qT, const bf16* __restrict__ kT,
    const bf16* __restrict__ vT, const unsigned char* __restrict__ mask8,
    float* __restrict__ attn_out, bf16* __restrict__ Oc) {
  extern __shared__ char smem[];             // [32][2048] bf16 P~ (128KB) + 1152B reductions
  float* red = (float*)(smem + 131072);

  // XCD-aware bijective swizzle: XCD x gets 128 consecutive works = exactly 2 (b,h) pairs.
  const int lbid = blockIdx.x;
  const int work = ((lbid & 7) << 7) + (lbid >> 3);
  const int bh = work >> 6;
  const int q0 = (work & 63) << 5;
  const int b = bh >> 3, h = bh & 7;
  const int tid = threadIdx.x;
  const int w = tid >> 6, lane = tid & 63, lo = lane & 15, hi = lane >> 4;

  const bf16* Qh = qT + (size_t)bh * SQ * HD;
  const bf16* Kh = kT + (size_t)bh * SQ * HD;
  const bf16* Vh = vT + (size_t)bh * HD * SQ;

  bf16x8 qf[2][4];                           // hoist Q tile (already scaled by 1/sqrt(D))
#pragma unroll
  for (int qs = 0; qs < 2; ++qs)
#pragma unroll
    for (int ks = 0; ks < 4; ++ks)
      qf[qs][ks] = ld8(Qh + (size_t)(q0 + qs * 16 + lo) * HD + ks * 32 + hi * 8);

  const f32x4 z4 = {0.f, 0.f, 0.f, 0.f};
  f32x4 acc[2][8];
#pragma unroll
  for (int qs = 0; qs < 2; ++qs)
#pragma unroll
    for (int ds = 0; ds < 8; ++ds) acc[qs][ds] = z4;

  float ssum0 = 0.f, ssum1 = 0.f;
  const int kvbase = w * 256;

  for (int it = 0; it < 8; ++it) {
    const int kvA = kvbase + it * 32;
    // ---- issue ALL 16 global loads of this iteration, then fence scheduling ----
    bf16x8 af0[4], af1[4], vf[8];
#pragma unroll
    for (int ks = 0; ks < 4; ++ks)
      af0[ks] = ld8(Kh + (size_t)(kvA + lo) * HD + ks * 32 + hi * 8);
#pragma unroll
    for (int ks = 0; ks < 4; ++ks)
      af1[ks] = ld8(Kh + (size_t)(kvA + 16 + lo) * HD + ks * 32 + hi * 8);
#pragma unroll
    for (int ds = 0; ds < 8; ++ds)
      vf[ds] = ld8(Vh + (size_t)(ds * 16 + lo) * SQ + kvA + hi * 8);
    __builtin_amdgcn_sched_barrier(0);       // loads stay above; 16 in flight together

    // ---- QK^T (swapped: A=K), mask, exp, stash P~ ----
#pragma unroll
    for (int t = 0; t < 2; ++t) {
      const int kvt = kvA + t * 16;
#pragma unroll
      for (int qs = 0; qs < 2; ++qs) {
        f32x4 c = z4;
#pragma unroll
        for (int ks = 0; ks < 4; ++ks)
          c = mfma16(t == 0 ? af0[ks] : af1[ks], qf[qs][ks], c);
        const int qg = q0 + qs * 16 + lo;
        const unsigned mu = *(const unsigned*)(mask8 + (size_t)qg * SQ + kvt + hi * 4);
        float p0 = __expf(c[0] * (0.5f + 0.5f * (float)(mu & 0xff)));
        float p1 = __expf(c[1] * (0.5f + 0.5f * (float)((mu >> 8) & 0xff)));
        float p2 = __expf(c[2] * (0.5f + 0.5f * (float)((mu >> 16) & 0xff)));
        float p3 = __expf(c[3] * (0.5f + 0.5f * (float)((mu >> 24) & 0xff)));
        const float ls = (p0 + p1) + (p2 + p3);
        if (qs == 0) ssum0 += ls; else ssum1 += ls;
        const int row = qs * 16 + lo;
        const unsigned sw = (unsigned)(row & 7) << 4;
        const unsigned byte0 = ((unsigned)row << 12) + (unsigned)(kvt + hi * 4) * 2;
        uint2 pk; pk.x = packbf2(p0, p1); pk.y = packbf2(p2, p3);
        *(uint2*)(smem + (byte0 ^ sw)) = pk;
      }
    }
    // ---- PV over these 32 kv (vf already in flight/arrived) ----
    __builtin_amdgcn_s_setprio(1);
#pragma unroll
    for (int qs = 0; qs < 2; ++qs) {
      const int row = qs * 16 + lo;
      const unsigned sw = (unsigned)(row & 7) << 4;
      const unsigned byteA = ((unsigned)row << 12) + (unsigned)kvA * 2 + (unsigned)hi * 16;
      bf16x8 pa = *(const bf16x8*)(smem + (byteA ^ sw));
#pragma unroll
      for (int ds = 0; ds < 8; ++ds) acc[qs][ds] = mfma16(pa, vf[ds], acc[qs][ds]);
    }
    __builtin_amdgcn_s_setprio(0);
  }

  // ---- softmax denominators (cross-hi then cross-wave) ----
  ssum0 += __shfl_xor(ssum0, 16); ssum0 += __shfl_xor(ssum0, 32);
  ssum1 += __shfl_xor(ssum1, 16); ssum1 += __shfl_xor(ssum1, 32);
  if (hi == 0) { red[w * 32 + lo] = ssum0; red[w * 32 + 16 + lo] = ssum1; }
  __syncthreads();
  if (tid < 32) {
    float t = 0.f;
#pragma unroll
    for (int ww = 0; ww < 8; ++ww) t += red[ww * 32 + tid];
    red[256 + tid] = 1.0f / t;
  }
  __syncthreads();

  // ---- phase 2: normalized attention, vectorized f32x4 nontemporal stores ----
  float* abase = attn_out + (size_t)bh * SQ * SQ + (size_t)q0 * SQ;
#pragma unroll 4
  for (int it2 = 0; it2 < 32; ++it2) {
    const int seg = it2 * 8 + w;             // 256 segments = 32 rows x 8 parts
    const int row = seg >> 3, part = seg & 7;
    const unsigned sw = (unsigned)(row & 7) << 4;
    const unsigned byte0 = ((unsigned)row << 12) + (unsigned)part * 512 + (unsigned)lane * 8;
    const uint2 pv = *(const uint2*)(smem + (byte0 ^ sw));
    const float rinv = red[256 + row];
    f32x4 o;
    o[0] = bflo(pv.x) * rinv; o[1] = bfhi(pv.x) * rinv;
    o[2] = bflo(pv.y) * rinv; o[3] = bfhi(pv.y) * rinv;
    __builtin_nontemporal_store(
        o, (f32x4*)(abase + (size_t)row * SQ + part * 256 + lane * 4));
  }
  __syncthreads();

  // ---- cross-wave O reduction (reuse P~ LDS) ----
  float* Op = (float*)smem;  // [8][32][128]
#pragma unroll
  for (int qs = 0; qs < 2; ++qs)
#pragma unroll
    for (int ds = 0; ds < 8; ++ds)
#pragma unroll
      for (int r = 0; r < 4; ++r)
        Op[(w * 32 + qs * 16 + hi * 4 + r) * 128 + ds * 16 + lo] = acc[qs][ds][r];
  __syncthreads();
  for (int e = tid; e < 32 * 128; e += 512) {
    const int q = e >> 7, d = e & 127;
    float s = 0.f;
#pragma unroll
    for (int ww = 0; ww < 8; ++ww) s += Op[ww * 4096 + e];
    Oc[(size_t)(b * SQ + q0 + q) * (NH * HD) + h * HD + d] = (bf16)(s * red[256 + q]);
  }
}

// ---------------- out@Wo + bo + x -> LayerNorm1 -> h (f32 + bf16) ----------------
__global__ __launch_bounds__(256, 4) void k_owo(
    const bf16* __restrict__ Oc, const bf16* __restrict__ WoT,
    const float* __restrict__ bo, const float* __restrict__ x,
    const float* __restrict__ g1, const float* __restrict__ be1,
    float* __restrict__ hf, bf16* __restrict__ hb) {
  __shared__ __align__(16) float hbuf[16 * 128];
  const int m0 = blockIdx.x * 16;
  const int tid = threadIdx.x;
  const int w = tid >> 6, lane = tid & 63, lo = lane & 15, hi = lane >> 4;
  const int nw = w * 32;
  const f32x4 z4 = {0.f, 0.f, 0.f, 0.f};
  f32x4 acc[2] = {z4, z4};
#pragma unroll 4
  for (int kk = 0; kk < 32; ++kk) {
    bf16x8 a = ld8(Oc + (size_t)(m0 + lo) * 1024 + kk * 32 + hi * 8);
#pragma unroll
    for (int ns = 0; ns < 2; ++ns) {
      bf16x8 bb = ld8(WoT + (size_t)(nw + ns * 16 + lo) * 1024 + kk * 32 + hi * 8);
      acc[ns] = mfma16(a, bb, acc[ns]);
    }
  }
#pragma unroll
  for (int ns = 0; ns < 2; ++ns) {
    const int n = nw + ns * 16 + lo;
    const float bia = bo[n];
#pragma unroll
    for (int r = 0; r < 4; ++r) {
      const int mr = hi * 4 + r;
      hbuf[mr * 128 + n] = acc[ns][r] + bia + x[(size_t)(m0 + mr) * 128 + n];
    }
  }
  __syncthreads();
  const float2 g = *(const float2*)(g1 + lane * 2);
  const float2 be = *(const float2*)(be1 + lane * 2);
#pragma unroll
  for (int rr = 0; rr < 4; ++rr) {
    const int row = w * 4 + rr;
    float2 v = *(float2*)&hbuf[row * 128 + lane * 2];
    float s = v.x + v.y, sq = v.x * v.x + v.y * v.y;
#pragma unroll
    for (int off = 32; off; off >>= 1) { s += __shfl_xor(s, off); sq += __shfl_xor(sq, off); }
    const float mean = s * (1.f / 128.f);
    const float var = sq * (1.f / 128.f) - mean * mean;
    const float rstd = rsqrtf(var + 1e-5f);
    const float y0 = (v.x - mean) * rstd * g.x + be.x;
    const float y1 = (v.y - mean) * rstd * g.y + be.y;
    const size_t o = (size_t)(m0 + row) * 128 + lane * 2;
    *(float2*)(hf + o) = make_float2(y0, y1);
    *(unsigned*)(hb + o) = packbf2(y0, y1);
  }
}

// ---------------- FFN (relu(h@W1+b1)@W2+b2) + residual -> LayerNorm2 -> y ----------------
__global__ __launch_bounds__(256, 4) void k_ffn(
    const bf16* __restrict__ hb, const float* __restrict__ hf,
    const bf16* __restrict__ W1T, const bf16* __restrict__ W2T,
    const float* __restrict__ b1, const float* __restrict__ b2,
    const float* __restrict__ g2, const float* __restrict__ be2,
    float* __restrict__ yout) {
  __shared__ __align__(16) bf16 s1[16 * 136];   // +8 pad per row: conflict-free b128 rereads
  __shared__ __align__(16) float ybuf[16 * 128];
  const int m0 = blockIdx.x * 16;
  const int tid = threadIdx.x;
  const int w = tid >> 6, lane = tid & 63, lo = lane & 15, hi = lane >> 4;
  const int nw = w * 32;
  const f32x4 z4 = {0.f, 0.f, 0.f, 0.f};
  f32x4 a1[2] = {z4, z4};
#pragma unroll
  for (int kk = 0; kk < 4; ++kk) {
    bf16x8 a = ld8(hb + (size_t)(m0 + lo) * 128 + kk * 32 + hi * 8);
#pragma unroll
    for (int ns = 0; ns < 2; ++ns)
      a1[ns] = mfma16(a, ld8(W1T + (size_t)(nw + ns * 16 + lo) * 128 + kk * 32 + hi * 8), a1[ns]);
  }
#pragma unroll
  for (int ns = 0; ns < 2; ++ns) {
    const int n = nw + ns * 16 + lo;
    const float bia = b1[n];
#pragma unroll
    for (int r = 0; r < 4; ++r)
      s1[(hi * 4 + r) * 136 + n] = (bf16)fmaxf(a1[ns][r] + bia, 0.f);
  }
  __syncthreads();
  f32x4 a2[2] = {z4, z4};
#pragma unroll
  for (int kk = 0; kk < 4; ++kk) {
    bf16x8 a = *(const bf16x8*)&s1[lo * 136 + kk * 32 + hi * 8];
#pragma unroll
    for (int ns = 0; ns < 2; ++ns)
      a2[ns] = mfma16(a, ld8(W2T + (size_t)(nw + ns * 16 + lo) * 128 + kk * 32 + hi * 8), a2[ns]);
  }
#pragma unroll
  for (int ns = 0; ns < 2; ++ns) {
    const int n = nw + ns * 16 + lo;
    const float bia = b2[n];
#pragma unroll
    for (int r = 0; r < 4; ++r) {
      const int mr = hi * 4 + r;
      ybuf[mr * 128 + n] = a2[ns][r] + bia + hf[(size_t)(m0 + mr) * 128 + n];
    }
  }
  __syncthreads();
  const float2 g = *(const float2*)(g2 + lane * 2);
  const float2 be = *(const float2*)(be2 + lane * 2);
#pragma unroll
  for (int rr = 0; rr < 4; ++rr) {
    const int row = w * 4 + rr;
    float2 v = *(float2*)&ybuf[row * 128 + lane * 2];
    float s = v.x + v.y, sq = v.x * v.x + v.y * v.y;
#pragma unroll
    for (int off = 32; off; off >>= 1) { s += __shfl_xor(s, off); sq += __shfl_xor(sq, off); }
    const float mean = s * (1.f / 128.f);
    const float var = sq * (1.f / 128.f) - mean * mean;
    const float rstd = rsqrtf(var + 1e-5f);
    const float y0 = (v.x - mean) * rstd * g.x + be.x;
    const float y1 = (v.y - mean) * rstd * g.y + be.y;
    *(float2*)(yout + (size_t)(m0 + row) * 128 + lane * 2) = make_float2(y0, y1);
  }
}

extern "C" void kernel_launch(void* const* d_in, const int* in_sizes, int n_in,
                              void* d_out, int out_size, void* d_ws, size_t ws_size,
                              hipStream_t stream) {
  const float* x  = (const float*)d_in[0];
  const int* adj  = (const int*)d_in[1];
  const float* Wq = (const float*)d_in[2];  const float* bq = (const float*)d_in[3];
  const float* Wk = (const float*)d_in[4];  const float* bk = (const float*)d_in[5];
  const float* Wv = (const float*)d_in[6];  const float* bv = (const float*)d_in[7];
  const float* Wo = (const float*)d_in[8];  const float* bo = (const float*)d_in[9];
  const float* g1 = (const float*)d_in[10]; const float* be1 = (const float*)d_in[11];
  const float* g2 = (const float*)d_in[12]; const float* be2 = (const float*)d_in[13];
  const float* W1 = (const float*)d_in[14]; const float* b1 = (const float*)d_in[15];
  const float* W2 = (const float*)d_in[16]; const float* b2 = (const float*)d_in[17];

  char* ws = (char*)d_ws;
  bf16* xb     = (bf16*)(ws + 0);
  bf16* WqkvT  = (bf16*)(ws + 1048576);
  bf16* WoT    = (bf16*)(ws + 1835008);
  bf16* W1T    = (bf16*)(ws + 2097152);
  bf16* W2T    = (bf16*)(ws + 2129920);
  unsigned char* mask8 = (unsigned char*)(ws + 2162688);
  bf16* qT     = (bf16*)(ws + 6356992);
  bf16* kT     = (bf16*)(ws + 14745600);
  bf16* vT     = (bf16*)(ws + 23134208);
  bf16* Oc     = (bf16*)(ws + 31522816);
  float* hf    = (float*)(ws + 39911424);
  bf16* hb     = (bf16*)(ws + 42008576);

  float* yout = (float*)d_out;
  float* attn_out = yout + (size_t)NROWS * HD;  // y first (524288 f32), then attn

  hipFuncSetAttribute((const void*)k_attn, hipFuncAttributeMaxDynamicSharedMemorySize, 132224);

  k_prep_a<<<6144, 256, 0, stream>>>(x, adj, xb, mask8);
  k_prep_w<<<2176, 256, 0, stream>>>(Wq, Wk, Wv, Wo, W1, W2, WqkvT, WoT, W1T, W2T);
  k_qkv<<<3072, 256, 0, stream>>>(xb, WqkvT, bq, bk, bv, qT, kT, vT);
  k_attn<<<1024, 512, 132224, stream>>>(qT, kT, vT, mask8, attn_out, Oc);
  k_owo<<<256, 256, 0, stream>>>(Oc, WoT, bo, x, g1, be1, hf, hb);
  k_ffn<<<256, 256, 0, stream>>>(hb, hf, W1T, W2T, b1, b2, g2, be2, yout);
}